// Round 1
// baseline (8983.521 us; speedup 1.0000x reference)
//
#include <hip/hip_runtime.h>
#include <stdint.h>

typedef __attribute__((ext_vector_type(8))) short short8;
typedef __attribute__((ext_vector_type(4))) float f32x4;

#define DEV static __device__ __forceinline__

DEV unsigned short f2bf(float f) {
  union { float f; uint32_t u; } v; v.f = f;
  uint32_t r = (v.u + 0x7fffu + ((v.u >> 16) & 1u)) >> 16;
  return (unsigned short)r;
}
DEV float bf2f(unsigned short h) {
  union { uint32_t u; float f; } v; v.u = ((uint32_t)h) << 16;
  return v.f;
}
DEV float fsigmoid(float x) { return 1.f / (1.f + __expf(-x)); }
DEV float ftanh(float x) {
  float e = __expf(2.f * x);
  return 1.f - 2.f / (e + 1.f);
}

// ---------------- output offsets (floats) ----------------
// output_ (64,100,512) | hT (64,512) | cT | haT | attns (100,64,1024) | paT (64,1024) | p_gen (64,100) | past_dehy (64,1,512) | loss (1)
static const size_t O_HT    = 3276800;
static const size_t O_CT    = 3309568;
static const size_t O_HAT   = 3342336;
static const size_t O_ATTNS = 3375104;
static const size_t O_PAT   = 9928704;
static const size_t O_PGEN  = 9994240;
static const size_t O_PDEHY = 10000640;
static const size_t O_LOSS  = 10033408;

// ---------------- setup kernels ----------------
__global__ __launch_bounds__(256) void k_conv_bf16(const float* __restrict__ in,
                                                   unsigned short* __restrict__ out) {
  size_t i = (size_t)blockIdx.x * blockDim.x + threadIdx.x;  // one f32x4 per thread
  f32x4 v = ((const f32x4*)in)[i];
  uint32_t lo = (uint32_t)f2bf(v[0]) | ((uint32_t)f2bf(v[1]) << 16);
  uint32_t hi = (uint32_t)f2bf(v[2]) | ((uint32_t)f2bf(v[3]) << 16);
  ((uint2*)out)[i] = make_uint2(lo, hi);
}

__global__ __launch_bounds__(256) void k_build_wcomb(const float* __restrict__ wih,
                                                     const float* __restrict__ whh,
                                                     unsigned short* __restrict__ wc) {
  int i = blockIdx.x * blockDim.x + threadIdx.x;  // 655360 threads, 4 elems each
  int base = i * 4;
  int n = base / 1280, k = base - n * 1280;
  const float* src = (k < 768) ? (wih + (size_t)n * 768 + k) : (whh + (size_t)n * 512 + (k - 768));
  f32x4 v = *(const f32x4*)src;
  uint32_t lo = (uint32_t)f2bf(v[0]) | ((uint32_t)f2bf(v[1]) << 16);
  uint32_t hi = (uint32_t)f2bf(v[2]) | ((uint32_t)f2bf(v[3]) << 16);
  ((uint2*)wc)[i] = make_uint2(lo, hi);
}

__global__ __launch_bounds__(256) void k_bias(const float* __restrict__ a,
                                              const float* __restrict__ b,
                                              float* __restrict__ o) {
  int i = blockIdx.x * blockDim.x + threadIdx.x;
  o[i] = a[i] + b[i];
}

// ---------------- MFMA GEMM: C = A(MxK,bf16) * B^T(NxK,bf16) + bias ----------------
template <int MT, int NT, int KK, int OUTBF>
__global__ __launch_bounds__(256) void k_gemm_bt(const unsigned short* __restrict__ A,
                                                 const unsigned short* __restrict__ Bm,
                                                 const float* __restrict__ bias,
                                                 void* __restrict__ C, int ldc) {
  int wid = (int)((blockIdx.x * blockDim.x + threadIdx.x) >> 6);
  int lane = threadIdx.x & 63;
  int tm = wid % MT, tn = wid / MT;
  int r = lane & 15, q = lane >> 4;
  const short8* Ap = (const short8*)(A + (size_t)(tm * 16 + r) * KK + q * 8);
  const short8* Bp = (const short8*)(Bm + (size_t)(tn * 16 + r) * KK + q * 8);
  f32x4 acc = {0.f, 0.f, 0.f, 0.f};
#pragma unroll 4
  for (int kk = 0; kk < KK / 32; ++kk) {
    acc = __builtin_amdgcn_mfma_f32_16x16x32_bf16(Ap[kk * 4], Bp[kk * 4], acc, 0, 0, 0);
  }
  int col = tn * 16 + r;
  float bv = bias ? bias[col] : 0.f;
#pragma unroll
  for (int rg = 0; rg < 4; ++rg) {
    int row = tm * 16 + q * 4 + rg;
    float v = acc[rg] + bv;
    if (OUTBF) ((unsigned short*)C)[(size_t)row * ldc + col] = f2bf(v);
    else       ((float*)C)[(size_t)row * ldc + col] = v;
  }
}

// ha = [c_enc(f32) | h(bf16)] @ w_ao^T + b_ao ; M=64,N=512,K=1024
__global__ __launch_bounds__(256) void k_gemm_ha(const float* __restrict__ cenc,
                                                 const unsigned short* __restrict__ hb,
                                                 const unsigned short* __restrict__ Bm,
                                                 const float* __restrict__ bias,
                                                 float* __restrict__ out) {
  int wid = (int)((blockIdx.x * blockDim.x + threadIdx.x) >> 6);
  int lane = threadIdx.x & 63;
  int tm = wid & 3, tn = wid >> 2;
  int r = lane & 15, q = lane >> 4;
  int arow = tm * 16 + r;
  f32x4 acc = {0.f, 0.f, 0.f, 0.f};
#pragma unroll
  for (int kk = 0; kk < 32; ++kk) {
    int k0 = kk * 32 + q * 8;
    short8 a;
    if (k0 < 512) {
      const f32x4* p = (const f32x4*)(cenc + (size_t)arow * 512 + k0);
      f32x4 lo = p[0], hi = p[1];
#pragma unroll
      for (int j = 0; j < 4; ++j) { a[j] = (short)f2bf(lo[j]); a[4 + j] = (short)f2bf(hi[j]); }
    } else {
      a = *(const short8*)(hb + (size_t)arow * 512 + (k0 - 512));
    }
    short8 b = *(const short8*)(Bm + (size_t)(tn * 16 + r) * 1024 + k0);
    acc = __builtin_amdgcn_mfma_f32_16x16x32_bf16(a, b, acc, 0, 0, 0);
  }
  int col = tn * 16 + r;
  float bv = bias[col];
#pragma unroll
  for (int rg = 0; rg < 4; ++rg) {
    int row = tm * 16 + q * 4 + rg;
    out[(size_t)row * 512 + col] = acc[rg] + bv;
  }
}

// ---------------- per-step kernels ----------------
__global__ __launch_bounds__(256) void k_pack(const float* __restrict__ input_,
                                              const float* __restrict__ ha,
                                              const float* __restrict__ h,
                                              unsigned short* __restrict__ xf, int t) {
  int idx = blockIdx.x * blockDim.x + threadIdx.x;  // 81920
  int b = idx / 1280, k = idx - b * 1280;
  float v;
  if (k < 256)      v = input_[((size_t)b * 100 + t) * 256 + k];
  else if (k < 768) v = ha[b * 512 + (k - 256)];
  else              v = h[b * 512 + (k - 768)];
  xf[idx] = f2bf(v);
}

__global__ __launch_bounds__(256) void k_lstm(const float* __restrict__ gates,
                                              float* __restrict__ h, float* __restrict__ c,
                                              unsigned short* __restrict__ hb) {
  int idx = blockIdx.x * blockDim.x + threadIdx.x;  // 32768
  int b = idx >> 9, n = idx & 511;
  const float* g = gates + (size_t)b * 2048;
  float iv = fsigmoid(g[n]);
  float fv = fsigmoid(g[512 + n]);
  float gv = ftanh(g[1024 + n]);
  float ov = fsigmoid(g[1536 + n]);
  float cn = fv * c[idx] + iv * gv;
  float hn = ov * ftanh(cn);
  c[idx] = cn; h[idx] = hn; hb[idx] = f2bf(hn);
}

__global__ __launch_bounds__(256) void k_attn_ee(const unsigned short* __restrict__ ep,
                                                 const float* __restrict__ de,
                                                 const float* __restrict__ cv,
                                                 const float* __restrict__ wwarp,
                                                 const float* __restrict__ pa,
                                                 float* __restrict__ ee) {
  int wid = (int)((blockIdx.x * blockDim.x + threadIdx.x) >> 6);  // one wave per (b,s)
  int lane = threadIdx.x & 63;
  int b = wid >> 10, s = wid & 1023;
  float pav = pa[(size_t)b * 1024 + s];
  short8 v = *(const short8*)(ep + ((size_t)b * 1024 + s) * 512 + lane * 8);
  const f32x4* dp = (const f32x4*)(de + b * 512 + lane * 8);
  f32x4 d0 = dp[0], d1 = dp[1];
  const f32x4* cp = (const f32x4*)(cv + lane * 8);
  f32x4 c0 = cp[0], c1 = cp[1];
  const f32x4* wp = (const f32x4*)(wwarp + lane * 8);
  f32x4 w0 = wp[0], w1 = wp[1];
  float acc = 0.f;
#pragma unroll
  for (int j = 0; j < 4; ++j) {
    float x0 = bf2f((unsigned short)v[j]) + d0[j] + pav * c0[j];
    acc += ftanh(x0) * w0[j];
    float x1 = bf2f((unsigned short)v[4 + j]) + d1[j] + pav * c1[j];
    acc += ftanh(x1) * w1[j];
  }
#pragma unroll
  for (int off = 32; off > 0; off >>= 1) acc += __shfl_xor(acc, off, 64);
  if (lane == 0) ee[(size_t)b * 1024 + s] = acc;
}

__global__ __launch_bounds__(256) void k_softmax(const float* __restrict__ ee,
                                                 float* __restrict__ attn,
                                                 float* __restrict__ attns_out,
                                                 float* __restrict__ pa,
                                                 float* __restrict__ cenc) {
  int b = blockIdx.x, tid = threadIdx.x;
  int wv = tid >> 6, lane = tid & 63;
  __shared__ float red[4];
  f32x4 v = ((const f32x4*)(ee + (size_t)b * 1024))[tid];
  float m = fmaxf(fmaxf(v[0], v[1]), fmaxf(v[2], v[3]));
#pragma unroll
  for (int off = 32; off > 0; off >>= 1) m = fmaxf(m, __shfl_xor(m, off, 64));
  if (lane == 0) red[wv] = m;
  __syncthreads();
  m = fmaxf(fmaxf(red[0], red[1]), fmaxf(red[2], red[3]));
  f32x4 e;
  e[0] = __expf(v[0] - m); e[1] = __expf(v[1] - m);
  e[2] = __expf(v[2] - m); e[3] = __expf(v[3] - m);
  float s = e[0] + e[1] + e[2] + e[3];
#pragma unroll
  for (int off = 32; off > 0; off >>= 1) s += __shfl_xor(s, off, 64);
  __syncthreads();
  if (lane == 0) red[wv] = s;
  __syncthreads();
  s = red[0] + red[1] + red[2] + red[3];
  float inv = 1.f / s;
  f32x4 a;
  a[0] = e[0] * inv; a[1] = e[1] * inv; a[2] = e[2] * inv; a[3] = e[3] * inv;
  ((f32x4*)(attn + (size_t)b * 1024))[tid] = a;
  ((f32x4*)(attns_out + (size_t)b * 1024))[tid] = a;
  f32x4* pap = (f32x4*)(pa + (size_t)b * 1024);
  f32x4 p = pap[tid];
  p[0] += a[0]; p[1] += a[1]; p[2] += a[2]; p[3] += a[3];
  pap[tid] = p;
  cenc[(size_t)b * 512 + tid] = 0.f;
  cenc[(size_t)b * 512 + 256 + tid] = 0.f;
}

__global__ __launch_bounds__(256) void k_cenc(const float* __restrict__ attn,
                                              const unsigned short* __restrict__ encb,
                                              float* __restrict__ cenc) {
  int b = blockIdx.x >> 2, sq = blockIdx.x & 3;
  int e0 = threadIdx.x * 2;
  const float* at = attn + (size_t)b * 1024 + sq * 256;
  const uint32_t* ep = (const uint32_t*)(encb + ((size_t)b * 1024 + sq * 256) * 512 + e0);
  float a0 = 0.f, a1 = 0.f;
#pragma unroll 4
  for (int s = 0; s < 256; ++s) {
    float w = at[s];
    uint32_t pk = ep[(size_t)s * 256];
    a0 += w * bf2f((unsigned short)(pk & 0xffffu));
    a1 += w * bf2f((unsigned short)(pk >> 16));
  }
  atomicAdd(&cenc[(size_t)b * 512 + e0], a0);
  atomicAdd(&cenc[(size_t)b * 512 + e0 + 1], a1);
}

__global__ __launch_bounds__(256) void k_pout(const float* __restrict__ input_,
                                              const float* __restrict__ h,
                                              const float* __restrict__ c,
                                              const float* __restrict__ cenc,
                                              const float* __restrict__ ha,
                                              const float* __restrict__ wpt,
                                              const float* __restrict__ bpt,
                                              float* __restrict__ dout, int t) {
  int b = blockIdx.x, tid = threadIdx.x;
  float acc = 0.f;
#pragma unroll
  for (int k = tid; k < 1280; k += 256) {
    float x;
    if (k < 256)      x = input_[((size_t)b * 100 + t) * 256 + k];
    else if (k < 768) x = h[(size_t)b * 512 + (k - 256)];
    else              x = cenc[(size_t)b * 512 + (k - 768)];
    acc += x * wpt[k];
  }
  int wv = tid >> 6, lane = tid & 63;
  __shared__ float red[4];
#pragma unroll
  for (int off = 32; off > 0; off >>= 1) acc += __shfl_xor(acc, off, 64);
  if (lane == 0) red[wv] = acc;
  __syncthreads();
  if (tid == 0) {
    float p = fsigmoid(red[0] + red[1] + red[2] + red[3] + bpt[0]);
    dout[O_PGEN + (size_t)b * 100 + t] = p;
  }
  float v0 = ha[(size_t)b * 512 + tid];
  float v1 = ha[(size_t)b * 512 + 256 + tid];
  dout[((size_t)b * 100 + t) * 512 + tid] = v0;
  dout[((size_t)b * 100 + t) * 512 + 256 + tid] = v1;
  if (t == 99) {
    dout[O_HT  + (size_t)b * 512 + tid]       = h[(size_t)b * 512 + tid];
    dout[O_HT  + (size_t)b * 512 + 256 + tid] = h[(size_t)b * 512 + 256 + tid];
    dout[O_CT  + (size_t)b * 512 + tid]       = c[(size_t)b * 512 + tid];
    dout[O_CT  + (size_t)b * 512 + 256 + tid] = c[(size_t)b * 512 + 256 + tid];
    dout[O_HAT + (size_t)b * 512 + tid]       = v0;
    dout[O_HAT + (size_t)b * 512 + 256 + tid] = v1;
  }
}

extern "C" void kernel_launch(void* const* d_in, const int* in_sizes, int n_in,
                              void* d_out, int out_size, void* d_ws, size_t ws_size,
                              hipStream_t stream) {
  const float* input_    = (const float*)d_in[1];
  const float* h0        = (const float*)d_in[2];
  const float* c0        = (const float*)d_in[3];
  const float* h_attn    = (const float*)d_in[4];
  const float* encoder_hy= (const float*)d_in[5];
  const float* past_attn = (const float*)d_in[6];
  const float* past_dehy = (const float*)d_in[7];
  const float* w_ih      = (const float*)d_in[8];
  const float* b_ih      = (const float*)d_in[9];
  const float* w_hh      = (const float*)d_in[10];
  const float* b_hh      = (const float*)d_in[11];
  const float* w_en      = (const float*)d_in[12];
  const float* b_en      = (const float*)d_in[13];
  const float* w_de      = (const float*)d_in[14];
  const float* w_cv      = (const float*)d_in[15];
  const float* w_warp    = (const float*)d_in[16];
  const float* w_ao      = (const float*)d_in[17];
  const float* b_ao      = (const float*)d_in[18];
  const float* w_pt      = (const float*)d_in[19];
  const float* b_pt      = (const float*)d_in[20];

  char* ws = (char*)d_ws;
  unsigned short* encb  = (unsigned short*)(ws + 0);           //  67,108,864 B
  unsigned short* epb   = (unsigned short*)(ws + 67108864);    //  67,108,864 B
  unsigned short* wcomb = (unsigned short*)(ws + 134217728);   //   5,242,880 B
  unsigned short* wenb  = (unsigned short*)(ws + 139460608);   //     524,288 B
  unsigned short* wdeb  = (unsigned short*)(ws + 139984896);   //     524,288 B
  unsigned short* waob  = (unsigned short*)(ws + 140509184);   //   1,048,576 B
  float* biasc          = (float*)(ws + 141557760);            //       8,192 B
  unsigned short* xf    = (unsigned short*)(ws + 141565952);   //     163,840 B
  float* gates          = (float*)(ws + 141729792);            //     524,288 B
  float* h              = (float*)(ws + 142254080);
  float* c              = (float*)(ws + 142385152);
  float* ha             = (float*)(ws + 142516224);
  unsigned short* hb    = (unsigned short*)(ws + 142647296);
  float* de             = (float*)(ws + 142712832);
  float* ee             = (float*)(ws + 142843904);
  float* attn           = (float*)(ws + 143106048);
  float* cenc           = (float*)(ws + 143368192);

  float* out = (float*)d_out;
  float* pa = out + O_PAT;  // pa state lives in the paT output slot

  // ---- init state ----
  hipMemcpyAsync(h,  h0,     32768 * 4, hipMemcpyDeviceToDevice, stream);
  hipMemcpyAsync(c,  c0,     32768 * 4, hipMemcpyDeviceToDevice, stream);
  hipMemcpyAsync(ha, h_attn, 32768 * 4, hipMemcpyDeviceToDevice, stream);
  hipMemcpyAsync(pa, past_attn, 65536 * 4, hipMemcpyDeviceToDevice, stream);
  hipMemcpyAsync(out + O_PDEHY, past_dehy, 32768 * 4, hipMemcpyDeviceToDevice, stream);
  hipMemsetAsync(out + O_LOSS, 0, 4, stream);

  // ---- one-time conversions + enc_proj ----
  k_conv_bf16<<<32768, 256, 0, stream>>>(encoder_hy, encb);   // 33.5M elems
  k_conv_bf16<<<256, 256, 0, stream>>>(w_en, wenb);
  k_conv_bf16<<<256, 256, 0, stream>>>(w_de, wdeb);
  k_conv_bf16<<<512, 256, 0, stream>>>(w_ao, waob);
  k_build_wcomb<<<2560, 256, 0, stream>>>(w_ih, w_hh, wcomb);
  k_bias<<<8, 256, 0, stream>>>(b_ih, b_hh, biasc);

  // enc_proj (65536x512, K=512) -> bf16
  k_gemm_bt<4096, 32, 512, 1><<<32768, 256, 0, stream>>>(encb, wenb, b_en, epb, 512);

  for (int t = 0; t < 100; ++t) {
    k_pack<<<320, 256, 0, stream>>>(input_, ha, h, xf, t);
    k_gemm_bt<4, 128, 1280, 0><<<128, 256, 0, stream>>>(xf, wcomb, biasc, gates, 2048);
    k_lstm<<<128, 256, 0, stream>>>(gates, h, c, hb);
    k_gemm_bt<4, 32, 512, 0><<<32, 256, 0, stream>>>(hb, wdeb, nullptr, de, 512);
    k_attn_ee<<<16384, 256, 0, stream>>>(epb, de, w_cv, w_warp, pa, ee);
    k_softmax<<<64, 256, 0, stream>>>(ee, attn, out + O_ATTNS + (size_t)t * 65536, pa, cenc);
    k_cenc<<<256, 256, 0, stream>>>(attn, encb, cenc);
    k_gemm_ha<<<32, 256, 0, stream>>>(cenc, hb, waob, b_ao, ha);
    k_pout<<<64, 256, 0, stream>>>(input_, h, c, cenc, ha, w_pt, b_pt, out, t);
  }
}